// Round 1
// baseline (282.327 us; speedup 1.0000x reference)
//
#include <hip/hip_runtime.h>
#include <hip/hip_bf16.h>
#include <math.h>

// Problem constants
#define B_   8
#define C_   128
#define H_   64
#define W_   64
#define MID_ 64
#define OC_  100   // (K_UP*SCALE)^2
#define HW_  4096  // 64*64
#define NSTAT_ 32768.0f  // 8*64*64 elements per channel

// ---------------- K1: 1x1 conv (x[8,128,64,64] * w[64,128]) -> t1[8,64,4096] ----------------
// grid 256 blocks: b(8) x chunk(16) x ochalf(2); 256 threads; each thread = 1 pixel, 32 oc accs.
__global__ __launch_bounds__(256) void k_conv1(const float* __restrict__ x,
                                               const float* __restrict__ w,
                                               float* __restrict__ t1) {
    int bi = blockIdx.x;
    int b = bi >> 5;
    int r = bi & 31;
    int chunk = r >> 1;
    int half = r & 1;
    int px = chunk * 256 + threadIdx.x;

    const float* xb = x + (size_t)b * C_ * HW_ + px;
    const float* wb = w + half * 32 * C_;

    float acc[32];
#pragma unroll
    for (int o = 0; o < 32; ++o) acc[o] = 0.f;

    for (int ic4 = 0; ic4 < 32; ++ic4) {
        float xv0 = xb[(ic4 * 4 + 0) * HW_];
        float xv1 = xb[(ic4 * 4 + 1) * HW_];
        float xv2 = xb[(ic4 * 4 + 2) * HW_];
        float xv3 = xb[(ic4 * 4 + 3) * HW_];
#pragma unroll
        for (int o = 0; o < 32; ++o) {
            const float4 wv = *(const float4*)(wb + o * C_ + ic4 * 4);
            acc[o] = fmaf(xv0, wv.x, acc[o]);
            acc[o] = fmaf(xv1, wv.y, acc[o]);
            acc[o] = fmaf(xv2, wv.z, acc[o]);
            acc[o] = fmaf(xv3, wv.w, acc[o]);
        }
    }
    float* t1p = t1 + (size_t)b * MID_ * HW_ + (size_t)half * 32 * HW_ + px;
#pragma unroll
    for (int o = 0; o < 32; ++o) t1p[o * HW_] = acc[o];
}

// ---------------- K2: per-channel sum / sumsq over [b][ch][4096] ----------------
__global__ __launch_bounds__(256) void k_stats(const float* __restrict__ src,
                                               float* __restrict__ sums,
                                               float* __restrict__ sqs, int nch) {
    int b = blockIdx.x / nch;
    int ch = blockIdx.x % nch;
    const float* p = src + (size_t)(b * nch + ch) * HW_ + threadIdx.x;
    float s = 0.f, q = 0.f;
#pragma unroll
    for (int i = 0; i < 16; ++i) {
        float v = p[i * 256];
        s += v;
        q += v * v;
    }
    for (int off = 32; off > 0; off >>= 1) {
        s += __shfl_down(s, off, 64);
        q += __shfl_down(q, off, 64);
    }
    __shared__ float ls[4], lq[4];
    int wid = threadIdx.x >> 6, lane = threadIdx.x & 63;
    if (lane == 0) { ls[wid] = s; lq[wid] = q; }
    __syncthreads();
    if (threadIdx.x == 0) {
        float S = ls[0] + ls[1] + ls[2] + ls[3];
        float Q = lq[0] + lq[1] + lq[2] + lq[3];
        atomicAdd(&sums[ch], S);
        atomicAdd(&sqs[ch], Q);
    }
}

// ---------------- K3: finalize BN -> scale/shift ----------------
__global__ void k_fin(const float* __restrict__ sums, const float* __restrict__ sqs,
                      const float* __restrict__ g, const float* __restrict__ bet,
                      float* __restrict__ scale, float* __restrict__ shift, int nch) {
    int c = threadIdx.x + blockIdx.x * blockDim.x;
    if (c < nch) {
        float invN = 1.0f / NSTAT_;
        float m = sums[c] * invN;
        float v = sqs[c] * invN - m * m;
        float rs = rsqrtf(v + 1e-5f);
        float sc = g[c] * rs;
        scale[c] = sc;
        shift[c] = bet[c] - m * sc;
    }
}

// ---------------- K4: 3x3 conv with fused BN+SiLU on input ----------------
// grid 512 = b(8) x tile(64 of 8x8); 256 threads; thread = (pxblock 2x2 of 16, ocg of 16) x 4 oc.
__global__ __launch_bounds__(256) void k_conv3(const float* __restrict__ t1,
                                               const float* __restrict__ wenc,
                                               const float* __restrict__ cscale,
                                               const float* __restrict__ cshift,
                                               float* __restrict__ t2) {
    __shared__ float xt[64 * 10 * 12];   // [ic][yy 10][xx pad 12]  30720 B
    __shared__ float wl[8 * 9 * 68];     // [ic*9+tap][oc pad 68]   19584 B

    int bi = blockIdx.x;
    int b = bi >> 6;
    int tile = bi & 63;
    int ty0 = (tile >> 3) * 8, tx0 = (tile & 7) * 8;
    const int tid = threadIdx.x;

    // stage x tile (apply BN + SiLU)
    const float* t1b = t1 + (size_t)b * MID_ * HW_;
#pragma unroll
    for (int i = 0; i < 25; ++i) {
        int s = tid + i * 256;           // 6400 = 64*100
        int ic = s / 100;
        int r = s - ic * 100;
        int yy = r / 10, xx = r - (r / 10) * 10;
        int gy = ty0 - 1 + yy, gx = tx0 - 1 + xx;
        float v = 0.f;
        if (gy >= 0 && gy < 64 && gx >= 0 && gx < 64) {
            float u = t1b[ic * HW_ + gy * 64 + gx];
            u = u * cscale[ic] + cshift[ic];
            v = u / (1.f + __expf(-u));
        }
        xt[ic * 120 + yy * 12 + xx] = v;
    }

    int pxb = tid & 15, ocg = tid >> 4;
    int px_ = (pxb & 3) * 2, py = (pxb >> 2) * 2;
    int ocl = tid & 63, g = tid >> 6;

    for (int pass = 0; pass < 2; ++pass) {
        int ocbase = pass * 64;
        bool active = (ocbase + ocg * 4) < OC_;
        float acc[2][2][4];
#pragma unroll
        for (int a0 = 0; a0 < 2; ++a0)
#pragma unroll
            for (int a1 = 0; a1 < 2; ++a1)
#pragma unroll
                for (int a2 = 0; a2 < 4; ++a2) acc[a0][a1][a2] = 0.f;

        for (int icc = 0; icc < 8; ++icc) {
            __syncthreads();
            {   // stage weights: wl[ict][ocl] = wenc[oc][icc*8 .. +8)(ic,tap)
                int oc = ocbase + ocl;
                const float* wp = wenc + (size_t)oc * 576 + icc * 72;
                bool okc = (oc < OC_);
#pragma unroll
                for (int i = 0; i < 18; ++i) {
                    int ict = g * 18 + i;      // 0..71
                    wl[ict * 68 + ocl] = okc ? wp[ict] : 0.f;
                }
            }
            __syncthreads();
            if (active) {
                for (int ic = 0; ic < 8; ++ic) {
                    float pr[4][4];
                    const float* xb = &xt[(icc * 8 + ic) * 120 + py * 12 + px_];
#pragma unroll
                    for (int ry = 0; ry < 4; ++ry) {
                        float2 a = *(const float2*)(xb + ry * 12);
                        float2 c2 = *(const float2*)(xb + ry * 12 + 2);
                        pr[ry][0] = a.x; pr[ry][1] = a.y; pr[ry][2] = c2.x; pr[ry][3] = c2.y;
                    }
#pragma unroll
                    for (int ky = 0; ky < 3; ++ky)
#pragma unroll
                        for (int kx = 0; kx < 3; ++kx) {
                            const float4 wv = *(const float4*)&wl[(ic * 9 + ky * 3 + kx) * 68 + ocg * 4];
#pragma unroll
                            for (int oy = 0; oy < 2; ++oy)
#pragma unroll
                                for (int ox = 0; ox < 2; ++ox) {
                                    float xv = pr[oy + ky][ox + kx];
                                    acc[oy][ox][0] = fmaf(xv, wv.x, acc[oy][ox][0]);
                                    acc[oy][ox][1] = fmaf(xv, wv.y, acc[oy][ox][1]);
                                    acc[oy][ox][2] = fmaf(xv, wv.z, acc[oy][ox][2]);
                                    acc[oy][ox][3] = fmaf(xv, wv.w, acc[oy][ox][3]);
                                }
                        }
                }
            }
        }
        if (active) {
#pragma unroll
            for (int o = 0; o < 4; ++o) {
                int oc = ocbase + ocg * 4 + o;
                if (oc < OC_) {
#pragma unroll
                    for (int oy = 0; oy < 2; ++oy) {
                        float2 st;
                        st.x = acc[oy][0][o];
                        st.y = acc[oy][1][o];
                        *(float2*)&t2[((size_t)b * OC_ + oc) * HW_ + (ty0 + py + oy) * 64 + tx0 + px_] = st;
                    }
                }
            }
        }
    }
}

// ---------------- K5: fused pixel-shuffle + BN + softmax + reassembly ----------------
// grid 512 = b(8) x tile(64 of 8x8 low-res); 256 threads = 16x16 hi-res pixels.
__global__ __launch_bounds__(256) void k_carafe(const float* __restrict__ x,
                                                const float* __restrict__ t2,
                                                const float* __restrict__ escale,
                                                const float* __restrict__ eshift,
                                                float* __restrict__ out) {
    __shared__ float xt[12 * 12 * 68];   // [yy*12+xx][c pad 68]  39168 B

    int bi = blockIdx.x;
    int b = bi >> 6;
    int tile = bi & 63;
    int ly0 = (tile >> 3) * 8, lx0 = (tile & 7) * 8;
    int tid = threadIdx.x;
    int hy = tid >> 4, hx = tid & 15;
    int i = ly0 * 2 + hy, j = lx0 * 2 + hx;
    int iy = ly0 + (hy >> 1), jx = lx0 + (hx >> 1);
    int s = (hy & 1) * 2 + (hx & 1);

    // softmax weights into 25 VGPRs
    float w[25];
    {
        const float* t2p = t2 + ((size_t)b * OC_ + s) * HW_ + iy * 64 + jx;
        float m = -1e30f;
#pragma unroll
        for (int k = 0; k < 25; ++k) {
            int ch = k * 4 + s;
            float v = fmaf(t2p[(size_t)k * 4 * HW_], escale[ch], eshift[ch]);
            w[k] = v;
            m = fmaxf(m, v);
        }
        float sum = 0.f;
#pragma unroll
        for (int k = 0; k < 25; ++k) { w[k] = __expf(w[k] - m); sum += w[k]; }
        float inv = 1.f / sum;
#pragma unroll
        for (int k = 0; k < 25; ++k) w[k] *= inv;
    }

    int jq = tid & 15, rq = tid >> 4;
    int ty = hy >> 1, tx = hx >> 1;
    float* outp = out + (size_t)b * C_ * 16384 + i * 128 + j;
    const float* xb = x + (size_t)b * C_ * HW_;

    for (int halfc = 0; halfc < 2; ++halfc) {
        __syncthreads();
        // stage 64 channels: xt[yy*12+xx][cl]
        for (int it = 0; it < 48; ++it) {
            int r = rq + it * 16;        // 768 rows = 64c * 12yy
            int cl = r / 12;
            int yy = r - cl * 12;
            int gy = ly0 - 2 + yy, gx = lx0 - 2 + jq;
            if (jq < 12) {
                float v = 0.f;
                if (gy >= 0 && gy < 64 && gx >= 0 && gx < 64)
                    v = xb[(size_t)(halfc * 64 + cl) * HW_ + gy * 64 + gx];
                xt[(yy * 12 + jq) * 68 + cl] = v;
            }
        }
        __syncthreads();
        // 4 channels per iteration via ds_read_b128
        for (int c0 = 0; c0 < 64; c0 += 4) {
            float ax = 0.f, ay = 0.f, az = 0.f, aw = 0.f;
#pragma unroll
            for (int dy = 0; dy < 5; ++dy)
#pragma unroll
                for (int dx = 0; dx < 5; ++dx) {
                    const float4 xv = *(const float4*)&xt[((ty + dy) * 12 + tx + dx) * 68 + c0];
                    float wk = w[dy * 5 + dx];
                    ax = fmaf(wk, xv.x, ax);
                    ay = fmaf(wk, xv.y, ay);
                    az = fmaf(wk, xv.z, az);
                    aw = fmaf(wk, xv.w, aw);
                }
            int c = halfc * 64 + c0;
            outp[(size_t)(c + 0) * 16384] = ax;
            outp[(size_t)(c + 1) * 16384] = ay;
            outp[(size_t)(c + 2) * 16384] = az;
            outp[(size_t)(c + 3) * 16384] = aw;
        }
    }
}

extern "C" void kernel_launch(void* const* d_in, const int* in_sizes, int n_in,
                              void* d_out, int out_size, void* d_ws, size_t ws_size,
                              hipStream_t stream) {
    const float* x      = (const float*)d_in[0];
    const float* comp_w = (const float*)d_in[1];
    const float* comp_g = (const float*)d_in[2];
    const float* comp_b = (const float*)d_in[3];
    const float* enc_w  = (const float*)d_in[4];
    const float* enc_g  = (const float*)d_in[5];
    const float* enc_b  = (const float*)d_in[6];
    float* out = (float*)d_out;

    float* ws = (float*)d_ws;
    float* t1 = ws;                         // 2,097,152 floats
    float* t2 = ws + 2097152;               // 3,276,800 floats
    float* stats = ws + 5373952;
    float* csum = stats;                    // 64
    float* csq  = stats + 64;               // 64
    float* esum = stats + 128;              // 100
    float* esq  = stats + 228;              // 100
    float* cscale = stats + 328;            // 64
    float* cshift = stats + 392;            // 64
    float* escale = stats + 456;            // 100
    float* eshift = stats + 556;            // 100

    hipMemsetAsync(stats, 0, 328 * sizeof(float), stream);

    k_conv1<<<256, 256, 0, stream>>>(x, comp_w, t1);
    k_stats<<<512, 256, 0, stream>>>(t1, csum, csq, MID_);
    k_fin<<<1, 64, 0, stream>>>(csum, csq, comp_g, comp_b, cscale, cshift, MID_);
    k_conv3<<<512, 256, 0, stream>>>(t1, enc_w, cscale, cshift, t2);
    k_stats<<<800, 256, 0, stream>>>(t2, esum, esq, OC_);
    k_fin<<<1, 128, 0, stream>>>(esum, esq, enc_g, enc_b, escale, eshift, OC_);
    k_carafe<<<512, 256, 0, stream>>>(x, t2, escale, eshift, out);
}

// Round 2
// 257.762 us; speedup vs baseline: 1.0953x; 1.0953x over previous
//
#include <hip/hip_runtime.h>
#include <hip/hip_bf16.h>
#include <math.h>

#define B_   8
#define C_   128
#define HW_  4096
#define MID_ 64
#define OC_  100
#define NSTAT_ 32768.0f

typedef __bf16 bf16x8 __attribute__((ext_vector_type(8)));
typedef __bf16 bf16x4 __attribute__((ext_vector_type(4)));
typedef float  f32x4  __attribute__((ext_vector_type(4)));

// ---------------- K1: 1x1 conv -> t1c[b][px][64] (channels-last fp32) + fused BN stats ------
// grid 256 = b(8) x chunk(16) x half(2); 256 thr; thread = 1 px, 32 oc accs.
__global__ __launch_bounds__(256) void k_conv1(const float* __restrict__ x,
                                               const float* __restrict__ w,
                                               float* __restrict__ t1c,
                                               float* __restrict__ csum,
                                               float* __restrict__ csq) {
    int bi = blockIdx.x;
    int b = bi >> 5;
    int r = bi & 31;
    int chunk = r >> 1;
    int half = r & 1;
    int px = chunk * 256 + threadIdx.x;

    const float* xb = x + (size_t)b * C_ * HW_ + px;
    const float* wb = w + half * 32 * C_;

    float acc[32];
#pragma unroll
    for (int o = 0; o < 32; ++o) acc[o] = 0.f;

    for (int ic4 = 0; ic4 < 32; ++ic4) {
        float xv0 = xb[(ic4 * 4 + 0) * HW_];
        float xv1 = xb[(ic4 * 4 + 1) * HW_];
        float xv2 = xb[(ic4 * 4 + 2) * HW_];
        float xv3 = xb[(ic4 * 4 + 3) * HW_];
#pragma unroll
        for (int o = 0; o < 32; ++o) {
            const float4 wv = *(const float4*)(wb + o * C_ + ic4 * 4);
            acc[o] = fmaf(xv0, wv.x, acc[o]);
            acc[o] = fmaf(xv1, wv.y, acc[o]);
            acc[o] = fmaf(xv2, wv.z, acc[o]);
            acc[o] = fmaf(xv3, wv.w, acc[o]);
        }
    }
    // channels-last store
    float* tp = t1c + ((size_t)b * HW_ + px) * 64 + half * 32;
#pragma unroll
    for (int o4 = 0; o4 < 8; ++o4) {
        float4 st;
        st.x = acc[o4 * 4 + 0]; st.y = acc[o4 * 4 + 1];
        st.z = acc[o4 * 4 + 2]; st.w = acc[o4 * 4 + 3];
        *(float4*)(tp + o4 * 4) = st;
    }
    // fused stats
    __shared__ float ls[4][32], lq[4][32];
    int wid = threadIdx.x >> 6, lane = threadIdx.x & 63;
#pragma unroll
    for (int o = 0; o < 32; ++o) {
        float s = acc[o];
        float q = s * s;
#pragma unroll
        for (int off = 32; off > 0; off >>= 1) {
            s += __shfl_down(s, off, 64);
            q += __shfl_down(q, off, 64);
        }
        if (lane == 0) { ls[wid][o] = s; lq[wid][o] = q; }
    }
    __syncthreads();
    if (threadIdx.x < 32) {
        int t = threadIdx.x;
        float S = ls[0][t] + ls[1][t] + ls[2][t] + ls[3][t];
        float Q = lq[0][t] + lq[1][t] + lq[2][t] + lq[3][t];
        atomicAdd(&csum[half * 32 + t], S);
        atomicAdd(&csq[half * 32 + t], Q);
    }
}

// ---------------- K_prep: repack enc_w -> wprep[oc 112][k 576] bf16, k = tap*64 + ic --------
__global__ void k_prep(const float* __restrict__ wenc, __bf16* __restrict__ wprep) {
    int idx = blockIdx.x * 256 + threadIdx.x;
    if (idx < 112 * 576) {
        int oc = idx / 576;
        int k = idx - oc * 576;
        int tap = k >> 6, ic = k & 63;
        float v = 0.f;
        if (oc < OC_) v = wenc[((size_t)oc * 64 + ic) * 9 + tap];
        wprep[idx] = (__bf16)v;
    }
}

// ---------------- K_fin: BN stats -> scale/shift ----------------
__global__ void k_fin(const float* __restrict__ sums, const float* __restrict__ sqs,
                      const float* __restrict__ g, const float* __restrict__ bet,
                      float* __restrict__ scale, float* __restrict__ shift, int nch) {
    int c = threadIdx.x + blockIdx.x * blockDim.x;
    if (c < nch) {
        float invN = 1.0f / NSTAT_;
        float m = sums[c] * invN;
        float v = sqs[c] * invN - m * m;
        float rs = rsqrtf(v + 1e-5f);
        float sc = g[c] * rs;
        scale[c] = sc;
        shift[c] = bet[c] - m * sc;
    }
}

// ---------------- K4: 3x3 conv via MFMA bf16 + fused stats -> t2c[b][px][112] --------------
// grid 256 = b(8) x tile(32: 8 ty x 4 tx of 8x16 px); 256 thr = 4 waves.
// M=128 px (8 rows x 16 cols), N=112 oc, K=576 = 9 taps x 64 ic (18 chunks of 32).
__global__ __launch_bounds__(256) void k_conv3(const float* __restrict__ t1c,
                                               const __bf16* __restrict__ wprep,
                                               const float* __restrict__ cscale,
                                               const float* __restrict__ cshift,
                                               float* __restrict__ t2c,
                                               float* __restrict__ esum,
                                               float* __restrict__ esq) {
    __shared__ __bf16 xt[10 * 18 * 72];   // halo [yy 10][xx 18][ic pad 72] bf16 = 25920 B
    __shared__ float esuml[112], esql[112];

    int bi = blockIdx.x;
    int b = bi >> 5;
    int tile = bi & 31;
    int ty0 = (tile >> 2) * 8, tx0 = (tile & 3) * 16;
    int tid = threadIdx.x;
    if (tid < 112) { esuml[tid] = 0.f; esql[tid] = 0.f; }

    // stage BN+SiLU(t1) halo -> LDS bf16  (2880 float4 jobs)
    const float* tb = t1c + (size_t)b * HW_ * 64;
#pragma unroll
    for (int it = 0; it < 12; ++it) {
        int idx = it * 256 + tid;
        if (idx < 2880) {
            int pxi = idx >> 4, f4 = idx & 15;
            int yy = pxi / 18, xx = pxi - yy * 18;
            int gy = ty0 + yy - 1, gx = tx0 + xx - 1;
            float4 o = {0.f, 0.f, 0.f, 0.f};
            if (gy >= 0 && gy < 64 && gx >= 0 && gx < 64) {
                float4 v = *(const float4*)(tb + ((size_t)(gy << 6) + gx) * 64 + f4 * 4);
                float4 sc = *(const float4*)(cscale + f4 * 4);
                float4 sh = *(const float4*)(cshift + f4 * 4);
                float u;
                u = fmaf(v.x, sc.x, sh.x); o.x = u / (1.f + __expf(-u));
                u = fmaf(v.y, sc.y, sh.y); o.y = u / (1.f + __expf(-u));
                u = fmaf(v.z, sc.z, sh.z); o.z = u / (1.f + __expf(-u));
                u = fmaf(v.w, sc.w, sh.w); o.w = u / (1.f + __expf(-u));
            }
            bf16x4 st;
            st[0] = (__bf16)o.x; st[1] = (__bf16)o.y; st[2] = (__bf16)o.z; st[3] = (__bf16)o.w;
            *(bf16x4*)&xt[pxi * 72 + f4 * 4] = st;
        }
    }
    __syncthreads();

    int lane = tid & 63, wv_ = tid >> 6;
    int p = lane & 15, q = lane >> 4;

    f32x4 acc[2][7];
#pragma unroll
    for (int mi = 0; mi < 2; ++mi)
#pragma unroll
        for (int n = 0; n < 7; ++n) acc[mi][n] = (f32x4){0.f, 0.f, 0.f, 0.f};

#pragma unroll
    for (int kk = 0; kk < 18; ++kk) {
        const int tap = kk >> 1, ich = (kk & 1) * 32;
        const int ky = tap / 3, kx = tap - ky * 3;
        bf16x8 a0 = *(const bf16x8*)&xt[((wv_ + ky) * 18 + p + kx) * 72 + ich + q * 8];
        bf16x8 a1 = *(const bf16x8*)&xt[((wv_ + 4 + ky) * 18 + p + kx) * 72 + ich + q * 8];
#pragma unroll
        for (int n = 0; n < 7; ++n) {
            bf16x8 bb = *(const bf16x8*)(wprep + ((size_t)(n * 16 + p)) * 576 + kk * 32 + q * 8);
            acc[0][n] = __builtin_amdgcn_mfma_f32_16x16x32_bf16(a0, bb, acc[0][n], 0, 0, 0);
            acc[1][n] = __builtin_amdgcn_mfma_f32_16x16x32_bf16(a1, bb, acc[1][n], 0, 0, 0);
        }
    }

    // store channels-last + fused stats.  D: col = lane&15 (oc), row = q*4+reg (x offset)
    float* t2b = t2c + (size_t)b * HW_ * 112;
#pragma unroll
    for (int n = 0; n < 7; ++n) {
        float s = 0.f, qq = 0.f;
#pragma unroll
        for (int mi = 0; mi < 2; ++mi) {
            int y = ty0 + wv_ + mi * 4;
            float* dst = t2b + ((size_t)y * 64 + tx0 + q * 4) * 112 + n * 16 + p;
#pragma unroll
            for (int rg = 0; rg < 4; ++rg) {
                float v = acc[mi][n][rg];
                dst[(size_t)rg * 112] = v;
                s += v; qq += v * v;
            }
        }
        s += __shfl_down(s, 32, 64);  s += __shfl_down(s, 16, 64);
        qq += __shfl_down(qq, 32, 64); qq += __shfl_down(qq, 16, 64);
        if (lane < 16) {
            atomicAdd(&esuml[n * 16 + lane], s);
            atomicAdd(&esql[n * 16 + lane], qq);
        }
    }
    __syncthreads();
    if (tid < 112) {
        atomicAdd(&esum[tid], esuml[tid]);
        atomicAdd(&esq[tid], esql[tid]);
    }
}

// ---------------- K5: fused BN + softmax + reassembly ----------------
// grid 512 = b(8) x tile(64 of 8x8 low-res); 256 thr = lpx(64) x cgrp(4 of 32ch).
// Each thread: one low-res px, all 4 sub-pixels (weights in regs), 32 channels.
__global__ __launch_bounds__(256, 2) void k_carafe(const float* __restrict__ x,
                                                   const float* __restrict__ t2c,
                                                   const float* __restrict__ esc,
                                                   const float* __restrict__ esh,
                                                   float* __restrict__ out) {
    __shared__ __bf16 xt[144 * 136];   // [px 12x12][ch pad 136] bf16 = 39168 B
    __shared__ float lsc[100], lsh[100];

    int bi = blockIdx.x;
    int b = bi >> 6;
    int tile = bi & 63;
    int ly0 = (tile >> 3) * 8, lx0 = (tile & 7) * 8;
    int tid = threadIdx.x;
    if (tid < 100) { lsc[tid] = esc[tid]; lsh[tid] = esh[tid]; }

    // stage x halo (12x12 x 128ch) -> LDS bf16 channels-last. 4608 jobs of 4 ch.
    const float* xb = x + (size_t)b * C_ * HW_;
#pragma unroll
    for (int it = 0; it < 18; ++it) {
        int idx = it * 256 + tid;
        int c4 = idx / 144;
        int r2 = idx - c4 * 144;
        int yy = r2 / 12, xx = r2 - yy * 12;
        int gy = ly0 - 2 + yy, gx = lx0 - 2 + xx;
        float v0 = 0.f, v1 = 0.f, v2 = 0.f, v3 = 0.f;
        if (gy >= 0 && gy < 64 && gx >= 0 && gx < 64) {
            size_t base = (size_t)(c4 * 4) * HW_ + (gy << 6) + gx;
            v0 = xb[base];
            v1 = xb[base + HW_];
            v2 = xb[base + 2 * HW_];
            v3 = xb[base + 3 * HW_];
        }
        bf16x4 st;
        st[0] = (__bf16)v0; st[1] = (__bf16)v1; st[2] = (__bf16)v2; st[3] = (__bf16)v3;
        *(bf16x4*)&xt[r2 * 136 + c4 * 4] = st;
    }
    __syncthreads();

    int lpx = tid & 63, cg = tid >> 6;
    int ty = lpx >> 3, tx = lpx & 7;
    int iy = ly0 + ty, jx = lx0 + tx;

    // softmax weights for 4 sub-pixels (25 each) in registers
    float wgt[4][25];
    {
        const float* t2p = t2c + ((size_t)((b << 12) + (iy << 6) + jx)) * 112;
        float mx0 = -1e30f, mx1 = -1e30f, mx2 = -1e30f, mx3 = -1e30f;
#pragma unroll
        for (int k = 0; k < 25; ++k) {
            float4 lv = *(const float4*)(t2p + k * 4);
            float l0 = fmaf(lv.x, lsc[4 * k + 0], lsh[4 * k + 0]);
            float l1 = fmaf(lv.y, lsc[4 * k + 1], lsh[4 * k + 1]);
            float l2 = fmaf(lv.z, lsc[4 * k + 2], lsh[4 * k + 2]);
            float l3 = fmaf(lv.w, lsc[4 * k + 3], lsh[4 * k + 3]);
            wgt[0][k] = l0; wgt[1][k] = l1; wgt[2][k] = l2; wgt[3][k] = l3;
            mx0 = fmaxf(mx0, l0); mx1 = fmaxf(mx1, l1);
            mx2 = fmaxf(mx2, l2); mx3 = fmaxf(mx3, l3);
        }
        float mxs[4] = {mx0, mx1, mx2, mx3};
#pragma unroll
        for (int s = 0; s < 4; ++s) {
            float sum = 0.f;
#pragma unroll
            for (int k = 0; k < 25; ++k) {
                float e = __expf(wgt[s][k] - mxs[s]);
                wgt[s][k] = e;
                sum += e;
            }
            float inv = 1.f / sum;
#pragma unroll
            for (int k = 0; k < 25; ++k) wgt[s][k] *= inv;
        }
    }

    float* ob = out + (size_t)b * C_ * 16384;
    int i0 = iy * 2, j0 = jx * 2;

#pragma unroll
    for (int c8 = 0; c8 < 4; ++c8) {
        int cbase = cg * 32 + c8 * 8;
        float acc[4][8];
#pragma unroll
        for (int s = 0; s < 4; ++s)
#pragma unroll
            for (int e = 0; e < 8; ++e) acc[s][e] = 0.f;

#pragma unroll
        for (int dy = 0; dy < 5; ++dy)
#pragma unroll
            for (int dx = 0; dx < 5; ++dx) {
                bf16x8 xv = *(const bf16x8*)&xt[((ty + dy) * 12 + tx + dx) * 136 + cbase];
                float xf[8];
#pragma unroll
                for (int e = 0; e < 8; ++e) xf[e] = (float)xv[e];
#pragma unroll
                for (int s = 0; s < 4; ++s) {
                    float wk = wgt[s][dy * 5 + dx];
#pragma unroll
                    for (int e = 0; e < 8; ++e) acc[s][e] = fmaf(wk, xf[e], acc[s][e]);
                }
            }
#pragma unroll
        for (int s = 0; s < 4; ++s) {
            int ii = i0 + (s >> 1), jj = j0 + (s & 1);
#pragma unroll
            for (int e = 0; e < 8; ++e)
                ob[(size_t)(cbase + e) * 16384 + ii * 128 + jj] = acc[s][e];
        }
    }
}

extern "C" void kernel_launch(void* const* d_in, const int* in_sizes, int n_in,
                              void* d_out, int out_size, void* d_ws, size_t ws_size,
                              hipStream_t stream) {
    const float* x      = (const float*)d_in[0];
    const float* comp_w = (const float*)d_in[1];
    const float* comp_g = (const float*)d_in[2];
    const float* comp_b = (const float*)d_in[3];
    const float* enc_w  = (const float*)d_in[4];
    const float* enc_g  = (const float*)d_in[5];
    const float* enc_b  = (const float*)d_in[6];
    float* out = (float*)d_out;

    float* ws = (float*)d_ws;
    float* t1c    = ws;                    // 2,097,152 floats
    float* t2c    = ws + 2097152;          // 3,670,016 floats
    float* st     = ws + 5767168;
    float* csum   = st;                    // 64
    float* csq    = st + 64;               // 64
    float* esum   = st + 128;              // 112
    float* esq    = st + 240;              // 112
    float* cscale = st + 352;              // 64
    float* cshift = st + 416;              // 64
    float* esc    = st + 480;              // 100
    float* esh    = st + 580;              // 100
    __bf16* wprep = (__bf16*)(st + 680);   // 112*576 bf16 = 129 KB

    hipMemsetAsync(st, 0, 352 * sizeof(float), stream);
    k_prep<<<252, 256, 0, stream>>>(enc_w, wprep);
    k_conv1<<<256, 256, 0, stream>>>(x, comp_w, t1c, csum, csq);
    k_fin<<<1, 64, 0, stream>>>(csum, csq, comp_g, comp_b, cscale, cshift, MID_);
    k_conv3<<<256, 256, 0, stream>>>(t1c, wprep, cscale, cshift, t2c, esum, esq);
    k_fin<<<1, 128, 0, stream>>>(esum, esq, enc_g, enc_b, esc, esh, OC_);
    k_carafe<<<512, 256, 0, stream>>>(x, t2c, esc, esh, out);
}

// Round 3
// 207.099 us; speedup vs baseline: 1.3632x; 1.2446x over previous
//
#include <hip/hip_runtime.h>
#include <hip/hip_bf16.h>
#include <math.h>

#define B_   8
#define C_   128
#define HW_  4096
#define MID_ 64
#define OC_  100
#define NSTAT_ 32768.0f

typedef __bf16 bf16x8 __attribute__((ext_vector_type(8)));
typedef __bf16 bf16x4 __attribute__((ext_vector_type(4)));
typedef float  f32x4  __attribute__((ext_vector_type(4)));

// ---------------- K1: 1x1 conv -> t1c[b][px][64] (channels-last) + stats; tail blocks pack w --
// grid 576: blocks 0..511 conv (b = bi&7 for XCD locality, 16 px-chunks x 4 oc-quarters),
//           blocks 512..575 repack enc_w -> wprep[oc 112][k 576] bf16 (k = tap*64+ic).
__global__ __launch_bounds__(256) void k_conv1(const float* __restrict__ x,
                                               const float* __restrict__ w,
                                               const float* __restrict__ wenc,
                                               float* __restrict__ t1c,
                                               float* __restrict__ csum,
                                               float* __restrict__ csq,
                                               __bf16* __restrict__ wprep) {
    int bi = blockIdx.x;
    if (bi >= 512) {
        int base = (bi - 512) * 1024 + threadIdx.x;
#pragma unroll
        for (int u = 0; u < 4; ++u) {
            int idx = base + u * 256;
            if (idx < 112 * 576) {
                int oc = idx / 576;
                int k = idx - oc * 576;
                int tap = k >> 6, ic = k & 63;
                float v = 0.f;
                if (oc < OC_) v = wenc[((size_t)oc * 64 + ic) * 9 + tap];
                wprep[idx] = (__bf16)v;
            }
        }
        return;
    }
    int b = bi & 7;
    int r = bi >> 3;            // 0..63
    int chunk = r >> 2;         // 16 chunks of 256 px
    int qtr = r & 3;            // 4 quarters of 16 oc
    int px = chunk * 256 + threadIdx.x;

    const float* xb = x + (size_t)b * C_ * HW_ + px;
    const float* wb = w + qtr * 16 * C_;

    float acc[16];
#pragma unroll
    for (int o = 0; o < 16; ++o) acc[o] = 0.f;

    for (int ic4 = 0; ic4 < 32; ++ic4) {
        float xv0 = xb[(ic4 * 4 + 0) * HW_];
        float xv1 = xb[(ic4 * 4 + 1) * HW_];
        float xv2 = xb[(ic4 * 4 + 2) * HW_];
        float xv3 = xb[(ic4 * 4 + 3) * HW_];
#pragma unroll
        for (int o = 0; o < 16; ++o) {
            const float4 wv = *(const float4*)(wb + o * C_ + ic4 * 4);
            acc[o] = fmaf(xv0, wv.x, acc[o]);
            acc[o] = fmaf(xv1, wv.y, acc[o]);
            acc[o] = fmaf(xv2, wv.z, acc[o]);
            acc[o] = fmaf(xv3, wv.w, acc[o]);
        }
    }
    float* tp = t1c + ((size_t)b * HW_ + px) * 64 + qtr * 16;
#pragma unroll
    for (int o4 = 0; o4 < 4; ++o4) {
        float4 st;
        st.x = acc[o4 * 4 + 0]; st.y = acc[o4 * 4 + 1];
        st.z = acc[o4 * 4 + 2]; st.w = acc[o4 * 4 + 3];
        *(float4*)(tp + o4 * 4) = st;
    }
    __shared__ float ls[4][16], lq[4][16];
    int wid = threadIdx.x >> 6, lane = threadIdx.x & 63;
#pragma unroll
    for (int o = 0; o < 16; ++o) {
        float s = acc[o];
        float q = s * s;
#pragma unroll
        for (int off = 32; off > 0; off >>= 1) {
            s += __shfl_down(s, off, 64);
            q += __shfl_down(q, off, 64);
        }
        if (lane == 0) { ls[wid][o] = s; lq[wid][o] = q; }
    }
    __syncthreads();
    if (threadIdx.x < 16) {
        int t = threadIdx.x;
        float S = ls[0][t] + ls[1][t] + ls[2][t] + ls[3][t];
        float Q = lq[0][t] + lq[1][t] + lq[2][t] + lq[3][t];
        atomicAdd(&csum[qtr * 16 + t], S);
        atomicAdd(&csq[qtr * 16 + t], Q);
    }
}

// ---------------- K4: 3x3 conv MFMA bf16, inline BN-finalize, fused stats ----------------
// grid 256 = b(8, XCD-resident) x tile(32: 8 ty x 4 tx of 8x16 px); 512 thr = 8 waves.
__global__ __launch_bounds__(512) void k_conv3(const float* __restrict__ t1c,
                                               const __bf16* __restrict__ wprep,
                                               const float* __restrict__ csum,
                                               const float* __restrict__ csq,
                                               const float* __restrict__ cg,
                                               const float* __restrict__ cb,
                                               float* __restrict__ t2c,
                                               float* __restrict__ esum,
                                               float* __restrict__ esq) {
    __shared__ __bf16 xt[10 * 18 * 72];   // [yy 10][xx 18][ic pad 72] bf16
    __shared__ float lsc[64], lsh[64];
    __shared__ float esuml[112], esql[112];

    int bi = blockIdx.x;
    int b = bi & 7;
    int tile = bi >> 3;
    int ty0 = (tile >> 2) * 8, tx0 = (tile & 3) * 16;
    int tid = threadIdx.x;
    if (tid < 112) { esuml[tid] = 0.f; esql[tid] = 0.f; }
    if (tid >= 128 && tid < 192) {
        int c = tid - 128;
        float invN = 1.0f / NSTAT_;
        float m = csum[c] * invN;
        float v = csq[c] * invN - m * m;
        float rs = rsqrtf(v + 1e-5f);
        float sc = cg[c] * rs;
        lsc[c] = sc;
        lsh[c] = cb[c] - m * sc;
    }
    __syncthreads();

    const float* tb = t1c + (size_t)b * HW_ * 64;
#pragma unroll
    for (int it = 0; it < 6; ++it) {
        int idx = it * 512 + tid;
        if (idx < 2880) {
            int pxi = idx >> 4, f4 = idx & 15;
            int yy = pxi / 18, xx = pxi - yy * 18;
            int gy = ty0 + yy - 1, gx = tx0 + xx - 1;
            float4 o = {0.f, 0.f, 0.f, 0.f};
            if (gy >= 0 && gy < 64 && gx >= 0 && gx < 64) {
                float4 v = *(const float4*)(tb + ((size_t)(gy << 6) + gx) * 64 + f4 * 4);
                float4 sc = *(const float4*)(lsc + f4 * 4);
                float4 sh = *(const float4*)(lsh + f4 * 4);
                float u;
                u = fmaf(v.x, sc.x, sh.x); o.x = u / (1.f + __expf(-u));
                u = fmaf(v.y, sc.y, sh.y); o.y = u / (1.f + __expf(-u));
                u = fmaf(v.z, sc.z, sh.z); o.z = u / (1.f + __expf(-u));
                u = fmaf(v.w, sc.w, sh.w); o.w = u / (1.f + __expf(-u));
            }
            bf16x4 st;
            st[0] = (__bf16)o.x; st[1] = (__bf16)o.y; st[2] = (__bf16)o.z; st[3] = (__bf16)o.w;
            *(bf16x4*)&xt[pxi * 72 + f4 * 4] = st;
        }
    }
    __syncthreads();

    int lane = tid & 63, wv_ = tid >> 6;   // wave = y row 0..7
    int p = lane & 15, q = lane >> 4;

    f32x4 acc[7];
#pragma unroll
    for (int n = 0; n < 7; ++n) acc[n] = (f32x4){0.f, 0.f, 0.f, 0.f};

#pragma unroll
    for (int kk = 0; kk < 18; ++kk) {
        const int tap = kk >> 1, ich = (kk & 1) * 32;
        const int ky = tap / 3, kx = tap - ky * 3;
        bf16x8 a0 = *(const bf16x8*)&xt[((wv_ + ky) * 18 + p + kx) * 72 + ich + q * 8];
#pragma unroll
        for (int n = 0; n < 7; ++n) {
            bf16x8 bb = *(const bf16x8*)(wprep + ((size_t)(n * 16 + p)) * 576 + kk * 32 + q * 8);
            acc[n] = __builtin_amdgcn_mfma_f32_16x16x32_bf16(a0, bb, acc[n], 0, 0, 0);
        }
    }

    // D: col(oc) = lane&15, row(x-offset) = q*4+reg
    float* t2b = t2c + (size_t)b * HW_ * 112;
    int y = ty0 + wv_;
#pragma unroll
    for (int n = 0; n < 7; ++n) {
        float s = 0.f, qq = 0.f;
        float* dst = t2b + ((size_t)y * 64 + tx0 + q * 4) * 112 + n * 16 + p;
#pragma unroll
        for (int rg = 0; rg < 4; ++rg) {
            float v = acc[n][rg];
            dst[(size_t)rg * 112] = v;
            s += v; qq += v * v;
        }
        s += __shfl_down(s, 32, 64);  s += __shfl_down(s, 16, 64);
        qq += __shfl_down(qq, 32, 64); qq += __shfl_down(qq, 16, 64);
        if (lane < 16) {
            atomicAdd(&esuml[n * 16 + lane], s);
            atomicAdd(&esql[n * 16 + lane], qq);
        }
    }
    __syncthreads();
    if (tid < 112) {
        atomicAdd(&esum[tid], esuml[tid]);
        atomicAdd(&esq[tid], esql[tid]);
    }
}

// ---------------- K5: fused BN-finalize + softmax + reassembly ----------------
// grid 512 = b(8, XCD-resident) x tile(64 of 8x8 low-res); 256 thr = lpx(64) x cgrp(4).
__global__ __launch_bounds__(256, 2) void k_carafe(const float* __restrict__ x,
                                                   const float* __restrict__ t2c,
                                                   const float* __restrict__ esum,
                                                   const float* __restrict__ esq,
                                                   const float* __restrict__ eg,
                                                   const float* __restrict__ eb,
                                                   float* __restrict__ out) {
    __shared__ __bf16 xt[144 * 136];   // [px 12x12][ch pad 136] bf16
    __shared__ float lsc[100], lsh[100];

    int bi = blockIdx.x;
    int b = bi & 7;
    int tile = bi >> 3;
    int ly0 = (tile >> 3) * 8, lx0 = (tile & 7) * 8;
    int tid = threadIdx.x;
    if (tid < 100) {
        float invN = 1.0f / NSTAT_;
        float m = esum[tid] * invN;
        float v = esq[tid] * invN - m * m;
        float rs = rsqrtf(v + 1e-5f);
        float sc = eg[tid] * rs;
        lsc[tid] = sc;
        lsh[tid] = eb[tid] - m * sc;
    }

    const float* xb = x + (size_t)b * C_ * HW_;
#pragma unroll
    for (int it = 0; it < 18; ++it) {
        int idx = it * 256 + tid;
        int c4 = idx / 144;
        int r2 = idx - c4 * 144;
        int yy = r2 / 12, xx = r2 - yy * 12;
        int gy = ly0 - 2 + yy, gx = lx0 - 2 + xx;
        float v0 = 0.f, v1 = 0.f, v2 = 0.f, v3 = 0.f;
        if (gy >= 0 && gy < 64 && gx >= 0 && gx < 64) {
            size_t base = (size_t)(c4 * 4) * HW_ + (gy << 6) + gx;
            v0 = xb[base];
            v1 = xb[base + HW_];
            v2 = xb[base + 2 * HW_];
            v3 = xb[base + 3 * HW_];
        }
        bf16x4 st;
        st[0] = (__bf16)v0; st[1] = (__bf16)v1; st[2] = (__bf16)v2; st[3] = (__bf16)v3;
        *(bf16x4*)&xt[r2 * 136 + c4 * 4] = st;
    }
    __syncthreads();

    int lpx = tid & 63, cg = tid >> 6;
    int ty = lpx >> 3, tx = lpx & 7;
    int iy = ly0 + ty, jx = lx0 + tx;

    float wgt[4][25];
    {
        const float* t2p = t2c + ((size_t)((b << 12) + (iy << 6) + jx)) * 112;
        float mx0 = -1e30f, mx1 = -1e30f, mx2 = -1e30f, mx3 = -1e30f;
#pragma unroll
        for (int k = 0; k < 25; ++k) {
            float4 lv = *(const float4*)(t2p + k * 4);
            float l0 = fmaf(lv.x, lsc[4 * k + 0], lsh[4 * k + 0]);
            float l1 = fmaf(lv.y, lsc[4 * k + 1], lsh[4 * k + 1]);
            float l2 = fmaf(lv.z, lsc[4 * k + 2], lsh[4 * k + 2]);
            float l3 = fmaf(lv.w, lsc[4 * k + 3], lsh[4 * k + 3]);
            wgt[0][k] = l0; wgt[1][k] = l1; wgt[2][k] = l2; wgt[3][k] = l3;
            mx0 = fmaxf(mx0, l0); mx1 = fmaxf(mx1, l1);
            mx2 = fmaxf(mx2, l2); mx3 = fmaxf(mx3, l3);
        }
        float mxs[4] = {mx0, mx1, mx2, mx3};
#pragma unroll
        for (int s = 0; s < 4; ++s) {
            float sum = 0.f;
#pragma unroll
            for (int k = 0; k < 25; ++k) {
                float e = __expf(wgt[s][k] - mxs[s]);
                wgt[s][k] = e;
                sum += e;
            }
            float inv = 1.f / sum;
#pragma unroll
            for (int k = 0; k < 25; ++k) wgt[s][k] *= inv;
        }
    }

    float* ob = out + (size_t)b * C_ * 16384;
    int i0 = iy * 2, j0 = jx * 2;

#pragma unroll
    for (int c8 = 0; c8 < 4; ++c8) {
        int cbase = cg * 32 + c8 * 8;
        float acc[4][8];
#pragma unroll
        for (int s = 0; s < 4; ++s)
#pragma unroll
            for (int e = 0; e < 8; ++e) acc[s][e] = 0.f;

#pragma unroll
        for (int dy = 0; dy < 5; ++dy)
#pragma unroll
            for (int dx = 0; dx < 5; ++dx) {
                bf16x8 xv = *(const bf16x8*)&xt[((ty + dy) * 12 + tx + dx) * 136 + cbase];
                float xf[8];
#pragma unroll
                for (int e = 0; e < 8; ++e) xf[e] = (float)xv[e];
#pragma unroll
                for (int s = 0; s < 4; ++s) {
                    float wk = wgt[s][dy * 5 + dx];
#pragma unroll
                    for (int e = 0; e < 8; ++e) acc[s][e] = fmaf(wk, xf[e], acc[s][e]);
                }
            }
        // coalesced float2 stores: full 64B sectors per 8 lanes
#pragma unroll
        for (int e = 0; e < 8; ++e) {
            float2 r0; r0.x = acc[0][e]; r0.y = acc[1][e];
            float2 r1; r1.x = acc[2][e]; r1.y = acc[3][e];
            float* rb = ob + (size_t)(cbase + e) * 16384;
            *(float2*)(rb + i0 * 128 + j0) = r0;
            *(float2*)(rb + (i0 + 1) * 128 + j0) = r1;
        }
    }
}

extern "C" void kernel_launch(void* const* d_in, const int* in_sizes, int n_in,
                              void* d_out, int out_size, void* d_ws, size_t ws_size,
                              hipStream_t stream) {
    const float* x      = (const float*)d_in[0];
    const float* comp_w = (const float*)d_in[1];
    const float* comp_g = (const float*)d_in[2];
    const float* comp_b = (const float*)d_in[3];
    const float* enc_w  = (const float*)d_in[4];
    const float* enc_g  = (const float*)d_in[5];
    const float* enc_b  = (const float*)d_in[6];
    float* out = (float*)d_out;

    float* ws = (float*)d_ws;
    float* t1c    = ws;                    // 2,097,152 floats
    float* t2c    = ws + 2097152;          // 3,670,016 floats
    float* st     = ws + 5767168;
    float* csum   = st;                    // 64
    float* csq    = st + 64;               // 64
    float* esum   = st + 128;              // 112
    float* esq    = st + 240;              // 112
    __bf16* wprep = (__bf16*)(st + 352);   // 112*576 bf16

    hipMemsetAsync(st, 0, 352 * sizeof(float), stream);
    k_conv1<<<576, 256, 0, stream>>>(x, comp_w, enc_w, t1c, csum, csq, wprep);
    k_conv3<<<256, 512, 0, stream>>>(t1c, wprep, csum, csq, comp_g, comp_b, t2c, esum, esq);
    k_carafe<<<512, 256, 0, stream>>>(x, t2c, esum, esq, enc_g, enc_b, out);
}